// Round 1
// baseline (67.268 us; speedup 1.0000x reference)
//
#include <hip/hip_runtime.h>
#include <hip/hip_bf16.h>
#include <math.h>

// Problem sizes (fixed by setup_inputs): B=4096, D=128, K=256, c=1.0
#define B_SZ 4096
#define D_SZ 128
#define K_SZ 256
#define MT   64          // m-tile (batch rows) per block
#define NT   64          // n-tile (k prototypes) per block
#define LSTR 136         // LDS row stride in bf16 elems (128 + 8 pad -> 272B = 17*16B, bank-friendly)
#define MIN_NORM 1e-15f

typedef __attribute__((ext_vector_type(8))) short  short8;   // MFMA A/B frag (8 bf16)
typedef __attribute__((ext_vector_type(4))) float  floatx4;  // MFMA C/D frag

static __device__ __forceinline__ unsigned short f2bf(float f) {
    union { float f; unsigned int u; } v; v.f = f;
    unsigned int u = v.u;
    u += 0x7FFFu + ((u >> 16) & 1u);   // round-to-nearest-even
    return (unsigned short)(u >> 16);
}
static __device__ __forceinline__ float bf2f(unsigned short h) {
    union { unsigned int u; float f; } v; v.u = ((unsigned int)h) << 16;
    return v.f;
}

__global__ __launch_bounds__(256) void mobius_mlr_kernel(
        const float* __restrict__ x, const float* __restrict__ p,
        const float* __restrict__ a, float* __restrict__ out) {
    __shared__ __align__(16) unsigned short lx[MT * LSTR];
    __shared__ __align__(16) unsigned short lp[NT * LSTR];
    __shared__ __align__(16) unsigned short la[NT * LSTR];
    __shared__ float xsq[MT];                 // |x_b|^2 per tile row
    __shared__ float p2s[NT], pas[NT], ans[NT]; // |p|^2, p.a, max(||a||,MIN_NORM) per tile col

    const int tid = threadIdx.x;
    const int mb0 = blockIdx.x * MT;
    const int nb0 = blockIdx.y * NT;

    // ---- stage X/P/A tiles: global f32 -> LDS bf16 (coalesced float4 loads) ----
    const float4* xg = (const float4*)x + (size_t)mb0 * (D_SZ / 4);
    const float4* pg = (const float4*)p + (size_t)nb0 * (D_SZ / 4);
    const float4* ag = (const float4*)a + (size_t)nb0 * (D_SZ / 4);
    #pragma unroll
    for (int j = 0; j < 8; ++j) {
        int idx = tid + j * 256;            // 0..2047 float4s (64 rows x 32)
        int row = idx >> 5;
        int c4  = idx & 31;
        float4 vx = xg[row * 32 + c4];
        float4 vp = pg[row * 32 + c4];
        float4 va = ag[row * 32 + c4];
        ushort4 sx = make_ushort4(f2bf(vx.x), f2bf(vx.y), f2bf(vx.z), f2bf(vx.w));
        ushort4 sp = make_ushort4(f2bf(vp.x), f2bf(vp.y), f2bf(vp.z), f2bf(vp.w));
        ushort4 sa = make_ushort4(f2bf(va.x), f2bf(va.y), f2bf(va.z), f2bf(va.w));
        *(ushort4*)&lx[row * LSTR + c4 * 4] = sx;
        *(ushort4*)&lp[row * LSTR + c4 * 4] = sp;
        *(ushort4*)&la[row * LSTR + c4 * 4] = sa;
    }
    __syncthreads();

    // ---- per-row / per-col stats (read-only on tiles; runs alongside nothing else) ----
    if (tid < 64) {
        // |x_row|^2
        float s = 0.f;
        const short8* r = (const short8*)&lx[tid * LSTR];
        #pragma unroll
        for (int i = 0; i < 16; ++i) {
            short8 v = r[i];
            #pragma unroll
            for (int e = 0; e < 8; ++e) { float f = bf2f((unsigned short)v[e]); s += f * f; }
        }
        xsq[tid] = s;
    } else if (tid < 128) {
        int k = tid - 64;
        float sp = 0.f, spa = 0.f;
        const short8* rp = (const short8*)&lp[k * LSTR];
        const short8* ra = (const short8*)&la[k * LSTR];
        #pragma unroll
        for (int i = 0; i < 16; ++i) {
            short8 vp = rp[i], va = ra[i];
            #pragma unroll
            for (int e = 0; e < 8; ++e) {
                float fp = bf2f((unsigned short)vp[e]);
                float fa = bf2f((unsigned short)va[e]);
                sp += fp * fp; spa += fp * fa;
            }
        }
        p2s[k] = sp; pas[k] = spa;
    } else if (tid < 192) {
        int k = tid - 128;
        float sa = 0.f;
        const short8* ra = (const short8*)&la[k * LSTR];
        #pragma unroll
        for (int i = 0; i < 16; ++i) {
            short8 va = ra[i];
            #pragma unroll
            for (int e = 0; e < 8; ++e) { float f = bf2f((unsigned short)va[e]); sa += f * f; }
        }
        ans[k] = fmaxf(sqrtf(sa), MIN_NORM);
    }

    // ---- MFMA: both GEMMs (X.P^T and X.A^T) for this 64x64 tile ----
    const int lane = tid & 63;
    const int wv   = tid >> 6;          // wave 0..3 -> m rows [wv*16, wv*16+16)
    const int quad = lane >> 4;
    const int r16  = lane & 15;
    const int arow = wv * 16 + r16;

    floatx4 accp[4], acca[4];
    #pragma unroll
    for (int j = 0; j < 4; ++j) {
        accp[j] = (floatx4){0.f, 0.f, 0.f, 0.f};
        acca[j] = (floatx4){0.f, 0.f, 0.f, 0.f};
    }

    #pragma unroll
    for (int dc = 0; dc < 4; ++dc) {
        int d0 = dc * 32 + quad * 8;
        short8 af = *(const short8*)&lx[arow * LSTR + d0];
        #pragma unroll
        for (int j = 0; j < 4; ++j) {
            short8 bp = *(const short8*)&lp[(j * 16 + r16) * LSTR + d0];
            short8 ba = *(const short8*)&la[(j * 16 + r16) * LSTR + d0];
            accp[j] = __builtin_amdgcn_mfma_f32_16x16x32_bf16(af, bp, accp[j], 0, 0, 0);
            acca[j] = __builtin_amdgcn_mfma_f32_16x16x32_bf16(af, ba, acca[j], 0, 0, 0);
        }
    }
    __syncthreads();   // stats visible to everyone

    // ---- fused epilogue ----
    // C/D layout (verified): col = lane&15, row = (lane>>4)*4 + reg
    #pragma unroll
    for (int j = 0; j < 4; ++j) {
        int coll = j * 16 + r16;
        float p2v = p2s[coll];
        float pav = pas[coll];
        float anv = ans[coll];
        #pragma unroll
        for (int r = 0; r < 4; ++r) {
            int rowl = wv * 16 + quad * 4 + r;
            float x2v = xsq[rowl];
            float pdx = accp[j][r];     // p_k . x_b
            float xda = acca[j][r];     // x_b . a_k
            // mobius_add(-p, x, c=1):  xy = -(p.x), x2 = |p|^2, y2 = |x|^2
            float alpha = 1.0f - 2.0f * pdx + x2v;          // 1 + 2c*xy + c*y2
            float beta  = 1.0f - p2v;                        // 1 - c*x2
            float den   = fmaxf(1.0f - 2.0f * pdx + p2v * x2v, MIN_NORM);
            float invd  = 1.0f / den;
            float sqn   = (alpha * alpha * p2v - 2.0f * alpha * beta * pdx
                           + beta * beta * x2v) * invd * invd;   // |mpx|^2
            sqn = fmaxf(sqn, MIN_NORM);
            float mda = (beta * xda - alpha * pav) * invd;       // mpx . a
            float dden = fmaxf((1.0f - sqn) * anv, MIN_NORM);
            float dist = asinhf(2.0f * mda / dden);
            out[(size_t)(mb0 + rowl) * K_SZ + (nb0 + coll)] = 2.0f * anv * dist;
        }
    }
}

extern "C" void kernel_launch(void* const* d_in, const int* in_sizes, int n_in,
                              void* d_out, int out_size, void* d_ws, size_t ws_size,
                              hipStream_t stream) {
    const float* x = (const float*)d_in[0];
    const float* p = (const float*)d_in[1];
    const float* a = (const float*)d_in[2];
    float* out = (float*)d_out;
    dim3 grid(B_SZ / MT, K_SZ / NT);   // (64, 4) = 256 blocks
    mobius_mlr_kernel<<<grid, dim3(256), 0, stream>>>(x, p, a, out);
}

// Round 2
// 63.355 us; speedup vs baseline: 1.0618x; 1.0618x over previous
//
#include <hip/hip_runtime.h>
#include <hip/hip_bf16.h>
#include <math.h>

// Problem sizes (fixed by setup_inputs): B=4096, D=128, K=256, c=1.0
#define B_SZ 4096
#define D_SZ 128
#define K_SZ 256
#define MT   32          // m-tile (batch rows) per block
#define NT   32          // n-tile (k prototypes) per block
#define LSTR 136         // LDS row stride in bf16 elems (272B, 16B-aligned rows)
#define MIN_NORM 1e-15f

typedef __attribute__((ext_vector_type(8))) short  short8;   // MFMA A/B frag (8 bf16)
typedef __attribute__((ext_vector_type(4))) float  floatx4;  // MFMA C/D frag

static __device__ __forceinline__ unsigned short f2bf(float f) {
    union { float f; unsigned int u; } v; v.f = f;
    unsigned int u = v.u;
    u += 0x7FFFu + ((u >> 16) & 1u);   // round-to-nearest-even
    return (unsigned short)(u >> 16);
}
static __device__ __forceinline__ float bf2f(unsigned short h) {
    union { unsigned int u; float f; } v; v.u = ((unsigned int)h) << 16;
    return v.f;
}

__global__ __launch_bounds__(256) void mobius_mlr_kernel(
        const float* __restrict__ x, const float* __restrict__ p,
        const float* __restrict__ a, float* __restrict__ out) {
    // 3 x (32 rows x 136 elems x 2B) = 26112 B LDS -> 4+ blocks/CU resident
    __shared__ __align__(16) unsigned short lx[MT * LSTR];
    __shared__ __align__(16) unsigned short lp[NT * LSTR];
    __shared__ __align__(16) unsigned short la[NT * LSTR];
    __shared__ float xsq[MT];                   // |x_b|^2
    __shared__ float p2s[NT], pas[NT], ans[NT]; // |p|^2, p.a, max(||a||,MIN_NORM)

    const int tid = threadIdx.x;
    const int mb0 = blockIdx.x * MT;
    const int nb0 = blockIdx.y * NT;

    // ---- stage tiles: global f32 -> LDS bf16 (coalesced float4 loads) ----
    // 32 rows x 32 float4 = 1024 float4 per array; 4 per thread per array
    const float4* xg = (const float4*)x + (size_t)mb0 * (D_SZ / 4);
    const float4* pg = (const float4*)p + (size_t)nb0 * (D_SZ / 4);
    const float4* ag = (const float4*)a + (size_t)nb0 * (D_SZ / 4);
    #pragma unroll
    for (int j = 0; j < 4; ++j) {
        int idx = tid + j * 256;            // == row*32 + c4
        int row = idx >> 5;
        int c4  = idx & 31;
        float4 vx = xg[idx];
        float4 vp = pg[idx];
        float4 va = ag[idx];
        *(ushort4*)&lx[row * LSTR + c4 * 4] =
            make_ushort4(f2bf(vx.x), f2bf(vx.y), f2bf(vx.z), f2bf(vx.w));
        *(ushort4*)&lp[row * LSTR + c4 * 4] =
            make_ushort4(f2bf(vp.x), f2bf(vp.y), f2bf(vp.z), f2bf(vp.w));
        *(ushort4*)&la[row * LSTR + c4 * 4] =
            make_ushort4(f2bf(va.x), f2bf(va.y), f2bf(va.z), f2bf(va.w));
    }
    __syncthreads();

    // ---- per-row / per-col stats: 4 threads per row, 32 elems each,
    //      butterfly-reduce over the 4-lane group ----
    if (tid < 128) {                       // waves 0-1: |x_row|^2, rows 0..31
        int row = tid >> 2, q = tid & 3;
        const short8* r = (const short8*)&lx[row * LSTR + q * 32];
        float s = 0.f;
        #pragma unroll
        for (int i = 0; i < 4; ++i) {
            short8 v = r[i];
            #pragma unroll
            for (int e = 0; e < 8; ++e) { float f = bf2f((unsigned short)v[e]); s += f * f; }
        }
        s += __shfl_xor(s, 1);
        s += __shfl_xor(s, 2);
        if (q == 0) xsq[row] = s;
    } else {                               // waves 2-3: p-stats, rows 0..31
        int t = tid - 128;
        int row = t >> 2, q = t & 3;
        const short8* rp = (const short8*)&lp[row * LSTR + q * 32];
        const short8* ra = (const short8*)&la[row * LSTR + q * 32];
        float sp = 0.f, spa = 0.f, sa2 = 0.f;
        #pragma unroll
        for (int i = 0; i < 4; ++i) {
            short8 vp = rp[i], va = ra[i];
            #pragma unroll
            for (int e = 0; e < 8; ++e) {
                float fp = bf2f((unsigned short)vp[e]);
                float fa = bf2f((unsigned short)va[e]);
                sp += fp * fp; spa += fp * fa; sa2 += fa * fa;
            }
        }
        sp  += __shfl_xor(sp, 1);  sp  += __shfl_xor(sp, 2);
        spa += __shfl_xor(spa, 1); spa += __shfl_xor(spa, 2);
        sa2 += __shfl_xor(sa2, 1); sa2 += __shfl_xor(sa2, 2);
        if (q == 0) {
            p2s[row] = sp; pas[row] = spa;
            ans[row] = fmaxf(sqrtf(sa2), MIN_NORM);
        }
    }

    // ---- MFMA: each wave computes one 16x16 quadrant of both GEMMs ----
    const int lane = tid & 63;
    const int wv   = tid >> 6;
    const int mi   = wv & 1;            // m-quadrant
    const int ni   = wv >> 1;           // n-quadrant
    const int quad = lane >> 4;
    const int r16  = lane & 15;

    floatx4 accp = {0.f, 0.f, 0.f, 0.f};
    floatx4 acca = {0.f, 0.f, 0.f, 0.f};
    #pragma unroll
    for (int dc = 0; dc < 4; ++dc) {
        int d0 = dc * 32 + quad * 8;
        short8 af = *(const short8*)&lx[(mi * 16 + r16) * LSTR + d0];
        short8 bp = *(const short8*)&lp[(ni * 16 + r16) * LSTR + d0];
        short8 ba = *(const short8*)&la[(ni * 16 + r16) * LSTR + d0];
        accp = __builtin_amdgcn_mfma_f32_16x16x32_bf16(af, bp, accp, 0, 0, 0);
        acca = __builtin_amdgcn_mfma_f32_16x16x32_bf16(af, ba, acca, 0, 0, 0);
    }
    __syncthreads();   // stats visible to everyone

    // ---- fused epilogue ----
    // C/D layout (verified): col = lane&15, row = (lane>>4)*4 + reg
    const int coll = ni * 16 + r16;
    const float p2v = p2s[coll];
    const float pav = pas[coll];
    const float anv = ans[coll];
    #pragma unroll
    for (int r = 0; r < 4; ++r) {
        int rowl = mi * 16 + quad * 4 + r;
        float x2v = xsq[rowl];
        float pdx = accp[r];        // p_k . x_b
        float xda = acca[r];        // x_b . a_k
        // mobius_add(-p, x, c=1): xy = -(p.x), x2 = |p|^2, y2 = |x|^2
        float alpha = 1.0f - 2.0f * pdx + x2v;
        float beta  = 1.0f - p2v;
        float den   = fmaxf(1.0f - 2.0f * pdx + p2v * x2v, MIN_NORM);
        float invd  = __builtin_amdgcn_rcpf(den);
        float sqn   = (alpha * alpha * p2v - 2.0f * alpha * beta * pdx
                       + beta * beta * x2v) * invd * invd;   // |mpx|^2
        sqn = fmaxf(sqn, MIN_NORM);
        float mda  = (beta * xda - alpha * pav) * invd;      // mpx . a
        float dden = fmaxf((1.0f - sqn) * anv, MIN_NORM);
        float z    = 2.0f * mda * __builtin_amdgcn_rcpf(dden);
        float dist = __logf(z + sqrtf(z * z + 1.0f));        // asinh(z), z ~ O(0.02)
        out[(size_t)(mb0 + rowl) * K_SZ + (nb0 + coll)] = 2.0f * anv * dist;
    }
}

extern "C" void kernel_launch(void* const* d_in, const int* in_sizes, int n_in,
                              void* d_out, int out_size, void* d_ws, size_t ws_size,
                              hipStream_t stream) {
    const float* x = (const float*)d_in[0];
    const float* p = (const float*)d_in[1];
    const float* a = (const float*)d_in[2];
    float* out = (float*)d_out;
    dim3 grid(B_SZ / MT, K_SZ / NT);   // (128, 8) = 1024 blocks -> 4 blocks/CU
    mobius_mlr_kernel<<<grid, dim3(256), 0, stream>>>(x, p, a, out);
}